// Round 21
// baseline (150.443 us; speedup 1.0000x reference)
//
#include <hip/hip_runtime.h>

// ============================ EVIDENCE LOG ============================
//  Facts: inputs fp32 time-major as shown; rows/cols int32; d_out FP32;
//    out=[out0|out1] each [Tp,n] flat; semantics = shown jnp ref (absmax
//    0.03-0.06 since R12). Sparse: gather rows[k], scatter cols[k].
//  R12 512 (atomic RMW amp). R13 197. R14 194 (1-WG CSR anti-pattern).
//  R15 149. R16 141.8. R17 202 (per-block edge build x495 = redundant).
//  R19 268 (grid.sync ~90us: XCD-L2 flush + 495-block spin).
//  R20 132.8 BEST: memset->prep(fill||transpose)->sparse_wave->final_fuse.
//    Top-5 all harness 0xAA ws-fills (268MB, ~42us) => harness-fixed ~77us;
//    ours ~56us over 5 nodes. Per-node removal saves ~4-5us (R16->R20).
//  THIS ROUND: merge sparse_wave INTO final_fuse (tile_fused): phase A =
//    bucket-edge sparse into LDS [c][i] via group-owns-county register
//    accumulation (R17's tile shape, WITHOUT its per-block edge build —
//    buckets prebuilt in prep); phase B = cov + native-M + coalesced store.
//    3 nodes total; kills one gap + 7.8MB wsS round-trip.
// ======================================================================

#define BS      256
#define ECAP    64
#define SPILLC  4096
#define SCAN_TH 1024

// ---- node 2: bucket-fill blocks || transpose-C/D blocks ----
__global__ void prep(const int* __restrict__ rows, const int* __restrict__ cols,
                     const float* __restrict__ Bnz, const float* __restrict__ Anz,
                     const float* __restrict__ Hnz,
                     const float* __restrict__ C, const float* __restrict__ D,
                     float* __restrict__ Ct, float* __restrict__ Dt,
                     float4* __restrict__ edges, int* __restrict__ cnt,
                     int* __restrict__ spill_cnt, int* __restrict__ spill,
                     int T, int NC, int NNZ, int fillBlocks, int cT64, int tT64) {
    if ((int)blockIdx.x < fillBlocks) {
        int k = blockIdx.x * BS + threadIdx.x;
        if (k < NNZ) {
            int c = cols[k];
            int j = atomicAdd(&cnt[c], 1);
            if (j < ECAP)
                edges[(size_t)c * ECAP + j] =
                    make_float4(__int_as_float(rows[k]), Bnz[k], Anz[k], Hnz[k]);
            else {
                int sp = atomicAdd(spill_cnt, 1);
                if (sp < SPILLC) spill[sp] = k;
            }
        }
        return;
    }
    __shared__ float tile[64][65];
    int bid = blockIdx.x - fillBlocks;
    int tTiles = cT64 * tT64;
    int z = bid / tTiles;
    int r = bid - z * tTiles;
    int ct = r / tT64, tt = r - ct * tT64;
    const float* src = z ? D : C;
    float* dst = z ? Dt : Ct;
    int lx = threadIdx.x & 63, ly = threadIdx.x >> 6;   // 64 x 4
    int c0 = ct * 64, t0 = tt * 64;
    for (int rr = ly; rr < 64; rr += 4) {
        int t = t0 + rr, c = c0 + lx;
        if (t < T && c < NC) tile[rr][lx] = src[(size_t)t * NC + c];
    }
    __syncthreads();
    for (int rr = ly; rr < 64; rr += 4) {
        int c = c0 + rr, t = t0 + lx;
        if (c < NC && t < T) dst[(size_t)c * T + t] = tile[lx][rr];
    }
}

// ---- node 3: tile_fused. One block per (32i x 32c) output tile. ----
// Phase A: group-owns-county sparse from prebuilt buckets -> LDS [c][i].
// Phase B: cov + mob (native-layout M) + coalesced stores. Spill = no-op.
#define FTI 32
#define FTC 32
__global__ __launch_bounds__(BS)
void tile_fused(const float* __restrict__ Ct,  // [NC, T]
                const float* __restrict__ Dt,  // [NC, T]
                const float* __restrict__ M,   // [NMOB, T, NC] native
                const float* __restrict__ cov, // [NCOV, NC]
                const float* __restrict__ mu,  // [NMOB, 2]
                const float* __restrict__ nu,
                const float* __restrict__ ups, const float* __restrict__ zet,
                const int* __restrict__ cnt, const float4* __restrict__ edges,
                const int* __restrict__ rows, const int* __restrict__ cols,
                const float* __restrict__ Bnz, const float* __restrict__ Anz,
                const float* __restrict__ Hnz,
                const int* __restrict__ spill_cnt, const int* __restrict__ spill,
                float* __restrict__ out0, float* __restrict__ out1,
                int T, int NC, int NMOB, int NCOV, int TPn, int cTiles) {
    __shared__ float s0[FTC][FTI + 1], s1[FTC][FTI + 1];   // [c][i], stride 33
    int bi = blockIdx.x / cTiles;
    int bc = blockIdx.x - bi * cTiles;
    int i0 = bi * FTI, c0 = bc * FTC;
    int tid = threadIdx.x;                 // 256

    // ---- phase A: sparse term, 8 groups x 32 i-lanes, group owns county ----
    {
        int grp = tid >> 5, li = tid & 31;
        int i = i0 + li;
        int isafe = (i < TPn) ? i : (TPn - 1);   // isafe+1 <= TPn < T: safe
        for (int cl = grp; cl < FTC; cl += 8) {
            float a0 = 0.f, a1 = 0.f;
            int c = c0 + cl;
            if (c < NC) {
                int n = cnt[c]; if (n > ECAP) n = ECAP;
                const float4* eb = edges + (size_t)c * ECAP;
                for (int j = 0; j < n; ++j) {
                    float4 E = eb[j];                // group-uniform broadcast
                    int g = __float_as_int(E.x);
                    const float* cr = Ct + (size_t)g * T;
                    const float* dr = Dt + (size_t)g * T;
                    float cs = cr[isafe] + cr[isafe + 1];   // 128B coalesced
                    float ds = dr[isafe] + dr[isafe + 1];
                    a0 += cs * E.y;
                    a1 += cs * E.w + ds * E.z;
                }
            }
            s0[cl][li] = a0;                         // owner-unique plain store
            s1[cl][li] = a1;
        }
    }
    __syncthreads();

    // ---- phase B: cov + mob native-M; lanes along c; coalesced stores ----
    int lc = tid & 31;
    int ri = tid >> 5;                     // 0..7
    int c = c0 + lc;
    if (c < NC) {
        float cv0 = 0.f, cv1 = 0.f;
        for (int j = 0; j < NCOV; ++j) {
            float cv = cov[(size_t)j * NC + c];
            cv0 += cv * ups[j];
            cv1 += cv * zet[j];
        }
        for (int ii = ri; ii < FTI; ii += 8) {
            int i = i0 + ii;
            if (i >= TPn) break;
            float a0 = s0[lc][ii] + cv0;   // stride-33: conflict-free
            float a1 = s1[lc][ii] + cv1;
            for (int k = 0; k < NMOB; ++k) {
                const float* mb = M + (size_t)k * T * NC;
                float m0 = mb[(size_t)i * NC + c];
                float m1 = mb[(size_t)(i + 1) * NC + c];
                a0 += m0 * mu[k * 2] + m1 * mu[k * 2 + 1];
                a1 += m0 * nu[k * 2] + m1 * nu[k * 2 + 1];
            }
            out0[(size_t)i * NC + c] = a0;
            out1[(size_t)i * NC + c] = a1;
        }
    }

    // ---- spill (bucket overflow — never in practice; correct path kept) ----
    int nsp = *spill_cnt;
    if (nsp > 0) {
        __syncthreads();
        if (nsp > SPILLC) nsp = SPILLC;
        int cmax = NC - c0; if (cmax > FTC) cmax = FTC;
        if (tid < FTI) {
            int io = i0 + tid;
            if (io < TPn) {
                for (int s = 0; s < nsp; ++s) {
                    int k = spill[s];
                    int cc = cols[k];
                    if (cc >= c0 && cc < c0 + cmax) {
                        int g = rows[k];
                        float cs = Ct[(size_t)g * T + io] + Ct[(size_t)g * T + io + 1];
                        float ds = Dt[(size_t)g * T + io] + Dt[(size_t)g * T + io + 1];
                        atomicAdd(&out0[(size_t)io * NC + cc], cs * Bnz[k]);
                        atomicAdd(&out1[(size_t)io * NC + cc], cs * Hnz[k] + ds * Anz[k]);
                    }
                }
            }
        }
    }
}

// ================= fallback path (P != 2): proven CSR chain =================
__global__ void csr_hist(const int* __restrict__ cols, int* __restrict__ counts, int NNZ) {
    int k = blockIdx.x * blockDim.x + threadIdx.x;
    if (k < NNZ) atomicAdd(&counts[cols[k]], 1);
}
__global__ __launch_bounds__(SCAN_TH)
void csr_scan(const int* __restrict__ counts, int* __restrict__ offsets,
              int* __restrict__ cursor, int NC) {
    __shared__ int ssum[SCAN_TH];
    int t = threadIdx.x;
    int chunk = (NC + SCAN_TH - 1) / SCAN_TH;
    int beg = t * chunk, end = min(beg + chunk, NC);
    int local = 0;
    for (int j = beg; j < end; ++j) local += counts[j];
    ssum[t] = local;
    __syncthreads();
    for (int off = 1; off < SCAN_TH; off <<= 1) {
        int v = (t >= off) ? ssum[t - off] : 0;
        __syncthreads();
        ssum[t] += v;
        __syncthreads();
    }
    int run = ssum[t] - local;
    for (int j = beg; j < end; ++j) {
        offsets[j] = run;
        cursor[j]  = run;
        run += counts[j];
    }
    if (t == SCAN_TH - 1) offsets[NC] = ssum[SCAN_TH - 1];
}
__global__ void csr_fill(const int* __restrict__ rows, const int* __restrict__ cols,
                         const float* __restrict__ Bnz, const float* __restrict__ Anz,
                         const float* __restrict__ Hnz,
                         int* __restrict__ cursor, float4* __restrict__ edges, int NNZ) {
    int k = blockIdx.x * blockDim.x + threadIdx.x;
    if (k >= NNZ) return;
    int s = cols[k];
    int pos = atomicAdd(&cursor[s], 1);
    edges[pos] = make_float4(__int_as_float(rows[k]), Bnz[k], Anz[k], Hnz[k]);
}
__global__ void fused_generic(const float* __restrict__ C, const float* __restrict__ D,
                              const float* __restrict__ M, const float* __restrict__ cov,
                              const float* __restrict__ mu, const float* __restrict__ nu,
                              const float* __restrict__ ups, const float* __restrict__ zet,
                              const int* __restrict__ offsets, const float4* __restrict__ edges,
                              float* __restrict__ out0, float* __restrict__ out1,
                              int T, int NC, int NMOB, int NCOV, int P, int TPn) {
    int idx = blockIdx.x * blockDim.x + threadIdx.x;
    if (idx >= TPn * NC) return;
    int i = idx / NC;
    int c = idx - i * NC;
    float acc0 = 0.f, acc1 = 0.f;
    for (int k = 0; k < NMOB; ++k)
        for (int tau = 0; tau < P; ++tau) {
            float m = M[((size_t)k * T + i + tau) * NC + c];
            acc0 += m * mu[k * P + tau];
            acc1 += m * nu[k * P + tau];
        }
    for (int j = 0; j < NCOV; ++j) {
        float cv = cov[(size_t)j * NC + c];
        acc0 += cv * ups[j];
        acc1 += cv * zet[j];
    }
    int e0 = offsets[c], e1 = offsets[c + 1];
    for (int e = e0; e < e1; ++e) {
        float4 E = edges[e];
        int g = __float_as_int(E.x);
        float cs = 0.f, ds = 0.f;
        for (int tau = 0; tau < P; ++tau) {
            cs += C[(size_t)(i + tau) * NC + g];
            ds += D[(size_t)(i + tau) * NC + g];
        }
        acc0 += cs * E.y;
        acc1 += cs * E.w + ds * E.z;
    }
    out0[idx] = acc0;
    out1[idx] = acc1;
}

extern "C" void kernel_launch(void* const* d_in, const int* in_sizes, int n_in,
                              void* d_out, int out_size, void* d_ws, size_t ws_size,
                              hipStream_t stream) {
    const float* C    = (const float*)d_in[0];
    const float* D    = (const float*)d_in[1];
    const float* M    = (const float*)d_in[2];
    const float* cov  = (const float*)d_in[3];
    const float* Bnz  = (const float*)d_in[4];
    const float* Anz  = (const float*)d_in[5];
    const float* Hnz  = (const float*)d_in[6];
    const float* mu   = (const float*)d_in[7];
    const float* nu   = (const float*)d_in[8];
    const float* ups  = (const float*)d_in[9];
    const float* zet  = (const float*)d_in[10];
    const int*  rows  = (const int*)d_in[11];
    const int*  cols  = (const int*)d_in[12];

    int NCOV = in_sizes[9];                 // 10
    int NC   = in_sizes[3] / NCOV;          // 3144
    int T    = in_sizes[0] / NC;            // 156
    int NMOB = in_sizes[2] / in_sizes[0];   // 6
    int P    = in_sizes[7] / NMOB;          // 2
    int NNZ  = in_sizes[11];                // 31440
    int TPn  = T - P;                       // 154

    float* out0 = (float*)d_out;            // fp32
    float* out1 = out0 + (size_t)TPn * NC;

    // ws: edges[NC*ECAP] | cnt[NC] | spillc[1] | spill[SPILLC] | Ct | Dt
    float4* edges  = (float4*)d_ws;
    int*    cnt    = (int*)(edges + (size_t)NC * ECAP);
    int*    spillc = cnt + NC;
    int*    spill  = spillc + 1;
    float*  Ct     = (float*)(spill + SPILLC);
    float*  Dt     = Ct + (size_t)NC * T;
    size_t  need   = (size_t)((char*)(Dt + (size_t)NC * T) - (char*)d_ws);

    if (P == 2 && ws_size >= need) {
        // node 1: zero cnt + spillc (adjacent) in one memset
        hipMemsetAsync(cnt, 0, (size_t)(NC + 1) * sizeof(int), stream);

        // node 2: bucket fill || transpose C,D
        int fillBlocks = (NNZ + BS - 1) / BS;                 // 123
        int cT64 = (NC + 63) / 64, tT64 = (T + 63) / 64;      // 50, 3
        prep<<<fillBlocks + 2 * cT64 * tT64, BS, 0, stream>>>(
            rows, cols, Bnz, Anz, Hnz, C, D, Ct, Dt,
            edges, cnt, spillc, spill, T, NC, NNZ, fillBlocks, cT64, tT64);

        // node 3: fused sparse + cov + mob + store
        int iTiles = (TPn + FTI - 1) / FTI;                   // 5
        int cTiles = (NC + FTC - 1) / FTC;                    // 99
        tile_fused<<<iTiles * cTiles, BS, 0, stream>>>(
            Ct, Dt, M, cov, mu, nu, ups, zet, cnt, edges,
            rows, cols, Bnz, Anz, Hnz, spillc, spill,
            out0, out1, T, NC, NMOB, NCOV, TPn, cTiles);
    } else {
        // fallback: proven CSR chain (handles any P)
        float4* fedges   = (float4*)d_ws;
        int*    foffsets = (int*)(fedges + NNZ);
        int*    fcounts  = foffsets + (NC + 1);
        int*    fcursor  = fcounts + NC;
        hipMemsetAsync(fcounts, 0, (size_t)NC * sizeof(int), stream);
        csr_hist<<<(NNZ + BS - 1) / BS, BS, 0, stream>>>(cols, fcounts, NNZ);
        csr_scan<<<1, SCAN_TH, 0, stream>>>(fcounts, foffsets, fcursor, NC);
        csr_fill<<<(NNZ + BS - 1) / BS, BS, 0, stream>>>(
            rows, cols, Bnz, Anz, Hnz, fcursor, fedges, NNZ);
        int n = TPn * NC;
        fused_generic<<<(n + BS - 1) / BS, BS, 0, stream>>>(
            C, D, M, cov, mu, nu, ups, zet, foffsets, fedges,
            out0, out1, T, NC, NMOB, NCOV, P, TPn);
    }
}

// Round 22
// 124.422 us; speedup vs baseline: 1.2091x; 1.2091x over previous
//
#include <hip/hip_runtime.h>

// ============================ EVIDENCE LOG ============================
//  Facts: inputs fp32 time-major as shown; rows/cols int32; d_out FP32;
//    out=[out0|out1] each [Tp,n] flat; semantics = shown jnp ref (absmax
//    0.03-0.06 since R12). Sparse: gather rows[k], scatter cols[k].
//  R12 512 (atomic RMW amp). R13 197. R14 194 (1-WG CSR). R15 149.
//  R16 141.8. R17 202 (per-block edge build). R19 268 (grid.sync ~90us).
//  R20 132.8 BEST: memset -> prep(fill||transposeCD) -> sparse_wave ->
//    final_fuse. Harness-fixed ~77us (268MB ws 0xAA fill = 43us @81% HBM).
//  R21 150.4 REGRESSION: merging sparse into the 495-block tile kernel cut
//    occupancy 37->8 waves/CU for the latency-bound gather phase (Occ 15%,
//    VALUBusy 5.5%, 52us). Fusion that cuts resident-wave parallelism on a
//    latency-bound phase loses > the ~12us it saves (4th consolidation
//    failure: R14/R17/R19/R21).
//  THIS ROUND: exact R20 revert + final_fuse M-reuse: contiguous 4-step ii
//    runs per thread with m0<-m1 register carry (M loads -37.5%); NMOB=6 /
//    NCOV=10 hardcoded on fast path (guarded; fallback generic else).
// ======================================================================

#define BS      256
#define ECAP    64
#define SPILLC  4096
#define SCAN_TH 1024

// ---- node 2: bucket-fill blocks || transpose-C/D blocks ----
__global__ void prep(const int* __restrict__ rows, const int* __restrict__ cols,
                     const float* __restrict__ Bnz, const float* __restrict__ Anz,
                     const float* __restrict__ Hnz,
                     const float* __restrict__ C, const float* __restrict__ D,
                     float* __restrict__ Ct, float* __restrict__ Dt,
                     float4* __restrict__ edges, int* __restrict__ cnt,
                     int* __restrict__ spill_cnt, int* __restrict__ spill,
                     int T, int NC, int NNZ, int fillBlocks, int cT64, int tT64) {
    if ((int)blockIdx.x < fillBlocks) {
        int k = blockIdx.x * BS + threadIdx.x;
        if (k < NNZ) {
            int c = cols[k];
            int j = atomicAdd(&cnt[c], 1);
            if (j < ECAP)
                edges[(size_t)c * ECAP + j] =
                    make_float4(__int_as_float(rows[k]), Bnz[k], Anz[k], Hnz[k]);
            else {
                int sp = atomicAdd(spill_cnt, 1);
                if (sp < SPILLC) spill[sp] = k;
            }
        }
        return;
    }
    __shared__ float tile[64][65];
    int bid = blockIdx.x - fillBlocks;
    int tTiles = cT64 * tT64;
    int z = bid / tTiles;
    int r = bid - z * tTiles;
    int ct = r / tT64, tt = r - ct * tT64;
    const float* src = z ? D : C;
    float* dst = z ? Dt : Ct;
    int lx = threadIdx.x & 63, ly = threadIdx.x >> 6;   // 64 x 4
    int c0 = ct * 64, t0 = tt * 64;
    for (int rr = ly; rr < 64; rr += 4) {
        int t = t0 + rr, c = c0 + lx;
        if (t < T && c < NC) tile[rr][lx] = src[(size_t)t * NC + c];
    }
    __syncthreads();
    for (int rr = ly; rr < 64; rr += 4) {
        int c = c0 + rr, t = t0 + lx;
        if (c < NC && t < T) dst[(size_t)c * T + t] = tile[lx][rr];
    }
}

// ---- node 3: sparse term. wave = (county, 64 time-lanes); bucket edges
// wave-uniform; Ct/Dt coalesced; ws stores coalesced [NC, TPn].
// 9432 waves (~37/CU) — high occupancy hides the L2 gather latency
// (R21 showed 8 waves/CU loses 2x on this phase). ----
__global__ void sparse_wave(const float* __restrict__ Ct, const float* __restrict__ Dt,
                            const int* __restrict__ cnt, const float4* __restrict__ edges,
                            float* __restrict__ wsS0, float* __restrict__ wsS1,
                            int T, int TPn, int nChunks, int nWaves) {
    int gtid = blockIdx.x * blockDim.x + threadIdx.x;
    int wid = gtid >> 6, lane = threadIdx.x & 63;
    if (wid >= nWaves) return;
    int c = wid / nChunks;
    int chunk = wid - c * nChunks;
    int i = chunk * 64 + lane;
    bool valid = i < TPn;
    int isafe = valid ? i : 0;            // isafe+1 <= TPn < T: safe
    float a0 = 0.f, a1 = 0.f;
    int n = cnt[c]; if (n > ECAP) n = ECAP;
    const float4* eb = edges + (size_t)c * ECAP;
    for (int j = 0; j < n; ++j) {
        float4 E = eb[j];                 // wave-uniform broadcast
        int g = __float_as_int(E.x);
        const float* cr = Ct + (size_t)g * T;
        const float* dr = Dt + (size_t)g * T;
        float cs = cr[isafe] + cr[isafe + 1];
        float ds = dr[isafe] + dr[isafe + 1];
        a0 += cs * E.y;
        a1 += cs * E.w + ds * E.z;
    }
    if (valid) {
        wsS0[(size_t)c * TPn + i] = a0;
        wsS1[(size_t)c * TPn + i] = a1;
    }
}

// ---- node 4: final fuse. NMOB=6, NCOV=10 hardcoded (host-guarded).
// Each thread owns a CONTIGUOUS run of 4 time steps: M row i+1 of step ii
// is reused as row i of step ii+1 via register carry (M loads -37.5%). ----
#define FTI 32
#define FTC 32
__global__ void final_fuse(const float* __restrict__ wsS0, const float* __restrict__ wsS1,
                           const float* __restrict__ M,   // [6, T, NC] native
                           const float* __restrict__ cov, // [10, NC]
                           const float* __restrict__ mu,  // [6, 2]
                           const float* __restrict__ nu,
                           const float* __restrict__ ups, const float* __restrict__ zet,
                           const float* __restrict__ Ct, const float* __restrict__ Dt,
                           const int* __restrict__ rows, const int* __restrict__ cols,
                           const float* __restrict__ Bnz, const float* __restrict__ Anz,
                           const float* __restrict__ Hnz,
                           const int* __restrict__ spill_cnt, const int* __restrict__ spill,
                           float* __restrict__ out0, float* __restrict__ out1,
                           int T, int NC, int TPn, int cTiles) {
    __shared__ float s0[FTI][FTC + 1], s1[FTI][FTC + 1];
    int bi = blockIdx.x / cTiles;
    int bc = blockIdx.x - bi * cTiles;
    int i0 = bi * FTI, c0 = bc * FTC;
    int tid = threadIdx.x;                // 256

    // phase 1: lanes along i (coalesced ws reads)
    {
        int li = tid & 31;
        int lc0 = tid >> 5;
        int i = i0 + li;
        for (int cc = lc0; cc < FTC; cc += 8) {
            int c = c0 + cc;
            float v0 = 0.f, v1 = 0.f;
            if (c < NC && i < TPn) {
                v0 = wsS0[(size_t)c * TPn + i];
                v1 = wsS1[(size_t)c * TPn + i];
            }
            s0[li][cc] = v0;
            s1[li][cc] = v1;
        }
    }
    __syncthreads();

    // phase 2: lanes along c; contiguous ii run of 4 with M register carry
    int lc = tid & 31;
    int ri = tid >> 5;                    // 0..7
    int c = c0 + lc;
    if (c < NC) {
        float cv0 = 0.f, cv1 = 0.f;
#pragma unroll
        for (int j = 0; j < 10; ++j) {
            float cv = cov[(size_t)j * NC + c];
            cv0 += cv * ups[j];
            cv1 += cv * zet[j];
        }
        int iiBeg = ri * 4;               // contiguous run [iiBeg, iiBeg+4)
        int iFirst = i0 + iiBeg;
        if (iFirst < TPn) {
            float m0r[6];
#pragma unroll
            for (int k = 0; k < 6; ++k)
                m0r[k] = M[((size_t)k * T + iFirst) * NC + c];
#pragma unroll
            for (int ii = 0; ii < 4; ++ii) {
                int i = iFirst + ii;
                if (i >= TPn) break;
                float a0 = s0[iiBeg + ii][lc] + cv0;
                float a1 = s1[iiBeg + ii][lc] + cv1;
#pragma unroll
                for (int k = 0; k < 6; ++k) {
                    float m1 = M[((size_t)k * T + i + 1) * NC + c];
                    a0 += m0r[k] * mu[k * 2] + m1 * mu[k * 2 + 1];
                    a1 += m0r[k] * nu[k * 2] + m1 * nu[k * 2 + 1];
                    m0r[k] = m1;          // carry: row i+1 becomes next row i
                }
                out0[(size_t)i * NC + c] = a0;
                out1[(size_t)i * NC + c] = a1;
            }
        }
    }

    // spill (bucket overflow — never in practice; correct path kept)
    int nsp = *spill_cnt;
    if (nsp > 0) {
        __syncthreads();
        if (nsp > SPILLC) nsp = SPILLC;
        int cmax = NC - c0; if (cmax > FTC) cmax = FTC;
        if (tid < FTI) {
            int io = i0 + tid;
            if (io < TPn) {
                for (int s = 0; s < nsp; ++s) {
                    int k = spill[s];
                    int cc = cols[k];
                    if (cc >= c0 && cc < c0 + cmax) {
                        int g = rows[k];
                        float cs = Ct[(size_t)g * T + io] + Ct[(size_t)g * T + io + 1];
                        float ds = Dt[(size_t)g * T + io] + Dt[(size_t)g * T + io + 1];
                        atomicAdd(&out0[(size_t)io * NC + cc], cs * Bnz[k]);
                        atomicAdd(&out1[(size_t)io * NC + cc], cs * Hnz[k] + ds * Anz[k]);
                    }
                }
            }
        }
    }
}

// ================= fallback path: proven CSR chain =================
__global__ void csr_hist(const int* __restrict__ cols, int* __restrict__ counts, int NNZ) {
    int k = blockIdx.x * blockDim.x + threadIdx.x;
    if (k < NNZ) atomicAdd(&counts[cols[k]], 1);
}
__global__ __launch_bounds__(SCAN_TH)
void csr_scan(const int* __restrict__ counts, int* __restrict__ offsets,
              int* __restrict__ cursor, int NC) {
    __shared__ int ssum[SCAN_TH];
    int t = threadIdx.x;
    int chunk = (NC + SCAN_TH - 1) / SCAN_TH;
    int beg = t * chunk, end = min(beg + chunk, NC);
    int local = 0;
    for (int j = beg; j < end; ++j) local += counts[j];
    ssum[t] = local;
    __syncthreads();
    for (int off = 1; off < SCAN_TH; off <<= 1) {
        int v = (t >= off) ? ssum[t - off] : 0;
        __syncthreads();
        ssum[t] += v;
        __syncthreads();
    }
    int run = ssum[t] - local;
    for (int j = beg; j < end; ++j) {
        offsets[j] = run;
        cursor[j]  = run;
        run += counts[j];
    }
    if (t == SCAN_TH - 1) offsets[NC] = ssum[SCAN_TH - 1];
}
__global__ void csr_fill(const int* __restrict__ rows, const int* __restrict__ cols,
                         const float* __restrict__ Bnz, const float* __restrict__ Anz,
                         const float* __restrict__ Hnz,
                         int* __restrict__ cursor, float4* __restrict__ edges, int NNZ) {
    int k = blockIdx.x * blockDim.x + threadIdx.x;
    if (k >= NNZ) return;
    int s = cols[k];
    int pos = atomicAdd(&cursor[s], 1);
    edges[pos] = make_float4(__int_as_float(rows[k]), Bnz[k], Anz[k], Hnz[k]);
}
__global__ void fused_generic(const float* __restrict__ C, const float* __restrict__ D,
                              const float* __restrict__ M, const float* __restrict__ cov,
                              const float* __restrict__ mu, const float* __restrict__ nu,
                              const float* __restrict__ ups, const float* __restrict__ zet,
                              const int* __restrict__ offsets, const float4* __restrict__ edges,
                              float* __restrict__ out0, float* __restrict__ out1,
                              int T, int NC, int NMOB, int NCOV, int P, int TPn) {
    int idx = blockIdx.x * blockDim.x + threadIdx.x;
    if (idx >= TPn * NC) return;
    int i = idx / NC;
    int c = idx - i * NC;
    float acc0 = 0.f, acc1 = 0.f;
    for (int k = 0; k < NMOB; ++k)
        for (int tau = 0; tau < P; ++tau) {
            float m = M[((size_t)k * T + i + tau) * NC + c];
            acc0 += m * mu[k * P + tau];
            acc1 += m * nu[k * P + tau];
        }
    for (int j = 0; j < NCOV; ++j) {
        float cv = cov[(size_t)j * NC + c];
        acc0 += cv * ups[j];
        acc1 += cv * zet[j];
    }
    int e0 = offsets[c], e1 = offsets[c + 1];
    for (int e = e0; e < e1; ++e) {
        float4 E = edges[e];
        int g = __float_as_int(E.x);
        float cs = 0.f, ds = 0.f;
        for (int tau = 0; tau < P; ++tau) {
            cs += C[(size_t)(i + tau) * NC + g];
            ds += D[(size_t)(i + tau) * NC + g];
        }
        acc0 += cs * E.y;
        acc1 += cs * E.w + ds * E.z;
    }
    out0[idx] = acc0;
    out1[idx] = acc1;
}

extern "C" void kernel_launch(void* const* d_in, const int* in_sizes, int n_in,
                              void* d_out, int out_size, void* d_ws, size_t ws_size,
                              hipStream_t stream) {
    const float* C    = (const float*)d_in[0];
    const float* D    = (const float*)d_in[1];
    const float* M    = (const float*)d_in[2];
    const float* cov  = (const float*)d_in[3];
    const float* Bnz  = (const float*)d_in[4];
    const float* Anz  = (const float*)d_in[5];
    const float* Hnz  = (const float*)d_in[6];
    const float* mu   = (const float*)d_in[7];
    const float* nu   = (const float*)d_in[8];
    const float* ups  = (const float*)d_in[9];
    const float* zet  = (const float*)d_in[10];
    const int*  rows  = (const int*)d_in[11];
    const int*  cols  = (const int*)d_in[12];

    int NCOV = in_sizes[9];                 // 10
    int NC   = in_sizes[3] / NCOV;          // 3144
    int T    = in_sizes[0] / NC;            // 156
    int NMOB = in_sizes[2] / in_sizes[0];   // 6
    int P    = in_sizes[7] / NMOB;          // 2
    int NNZ  = in_sizes[11];                // 31440
    int TPn  = T - P;                       // 154

    float* out0 = (float*)d_out;            // fp32
    float* out1 = out0 + (size_t)TPn * NC;

    // ws: edges[NC*ECAP] | cnt[NC] | spillc[1] | spill[SPILLC] | Ct | Dt | wsS0 | wsS1
    float4* edges  = (float4*)d_ws;
    int*    cnt    = (int*)(edges + (size_t)NC * ECAP);
    int*    spillc = cnt + NC;
    int*    spill  = spillc + 1;
    float*  Ct     = (float*)(spill + SPILLC);
    float*  Dt     = Ct + (size_t)NC * T;
    float*  wsS0   = Dt + (size_t)NC * T;
    float*  wsS1   = wsS0 + (size_t)NC * TPn;
    size_t  need   = (size_t)((char*)(wsS1 + (size_t)NC * TPn) - (char*)d_ws);

    if (P == 2 && NMOB == 6 && NCOV == 10 && ws_size >= need) {
        // node 1: zero cnt + spillc (adjacent) in one memset
        hipMemsetAsync(cnt, 0, (size_t)(NC + 1) * sizeof(int), stream);

        // node 2: bucket fill || transpose C,D
        int fillBlocks = (NNZ + BS - 1) / BS;                 // 123
        int cT64 = (NC + 63) / 64, tT64 = (T + 63) / 64;      // 50, 3
        prep<<<fillBlocks + 2 * cT64 * tT64, BS, 0, stream>>>(
            rows, cols, Bnz, Anz, Hnz, C, D, Ct, Dt,
            edges, cnt, spillc, spill, T, NC, NNZ, fillBlocks, cT64, tT64);

        // node 3: sparse term from buckets (high-occupancy wave kernel)
        int nChunks = (TPn + 63) / 64;                        // 3
        int nWaves  = NC * nChunks;                           // 9432
        sparse_wave<<<(nWaves * 64 + BS - 1) / BS, BS, 0, stream>>>(
            Ct, Dt, cnt, edges, wsS0, wsS1, T, TPn, nChunks, nWaves);

        // node 4: cov + mob + store (M register-carry reuse)
        int iTiles = (TPn + FTI - 1) / FTI;                   // 5
        int cTiles = (NC + FTC - 1) / FTC;                    // 99
        final_fuse<<<iTiles * cTiles, BS, 0, stream>>>(
            wsS0, wsS1, M, cov, mu, nu, ups, zet, Ct, Dt,
            rows, cols, Bnz, Anz, Hnz, spillc, spill,
            out0, out1, T, NC, TPn, cTiles);
    } else {
        // fallback: proven CSR chain (handles any P/NMOB/NCOV)
        float4* fedges   = (float4*)d_ws;
        int*    foffsets = (int*)(fedges + NNZ);
        int*    fcounts  = foffsets + (NC + 1);
        int*    fcursor  = fcounts + NC;
        hipMemsetAsync(fcounts, 0, (size_t)NC * sizeof(int), stream);
        csr_hist<<<(NNZ + BS - 1) / BS, BS, 0, stream>>>(cols, fcounts, NNZ);
        csr_scan<<<1, SCAN_TH, 0, stream>>>(fcounts, foffsets, fcursor, NC);
        csr_fill<<<(NNZ + BS - 1) / BS, BS, 0, stream>>>(
            rows, cols, Bnz, Anz, Hnz, fcursor, fedges, NNZ);
        int n = TPn * NC;
        fused_generic<<<(n + BS - 1) / BS, BS, 0, stream>>>(
            C, D, M, cov, mu, nu, ups, zet, foffsets, fedges,
            out0, out1, T, NC, NMOB, NCOV, P, TPn);
    }
}